// Round 3
// baseline (2541.351 us; speedup 1.0000x reference)
//
#include <hip/hip_runtime.h>
#include <hip/hip_bf16.h>

// SimpleMHA  B=2 T=2048 D=512 H=8 DK=64  -- ALL fp32 per reference dtypes.
// outputs: out [B,T,D] fp32, then A [B,H,T,T] fp32, concatenated in d_out.
#define BB 2
#define TT 2048
#define DD 512
#define HH 8
#define DKK 64
#define QB 4

typedef __hip_bfloat16 bf16;
typedef __bf16 bf16x8 __attribute__((ext_vector_type(8)));
typedef float f32x4 __attribute__((ext_vector_type(4)));

// Y[m][n] = sum_k X[m][k] * W[n][k] + bias[n]   (Y = X @ W^T + b)
// X: [M,K] fp32 row-major, W: [N,K] fp32 row-major. fp32 -> bf16 conversion
// happens during LDS staging; compute is bf16 MFMA (rel err ~0.3% << 2% thr).
// 64x64 block tile, 4 waves: wave w does rows [16w,16w+16), all 4 col-tiles.
__global__ __launch_bounds__(256) void gemm_bt(const float* __restrict__ X,
                                               const float* __restrict__ W,
                                               const float* __restrict__ bias,
                                               float* __restrict__ Y,
                                               int M, int N, int K) {
    const int m0 = blockIdx.x * 64;
    const int n0 = blockIdx.y * 64;
    const int t = threadIdx.x;
    const int wave = t >> 6;
    const int lane = t & 63;
    const int ln = lane & 15;
    const int qd = lane >> 4;

    // pitch 40 bf16 (80 B): 2-way bank aliasing on ds_read_b128 (free, m136)
    __shared__ __align__(16) __bf16 Xs[64 * 40];
    __shared__ __align__(16) __bf16 Ws[64 * 40];

    f32x4 acc[4];
    for (int c = 0; c < 4; ++c) acc[c] = (f32x4){0.f, 0.f, 0.f, 0.f};

    const int lrow = t >> 2;     // 0..63
    const int lk = (t & 3) * 8;  // 0,8,16,24

    for (int k0 = 0; k0 < K; k0 += 32) {
        __syncthreads();
        {
            const float4* xp = (const float4*)(X + (size_t)(m0 + lrow) * K + k0 + lk);
            const float4* wp = (const float4*)(W + (size_t)(n0 + lrow) * K + k0 + lk);
            const float4 x0 = xp[0], x1 = xp[1];
            const float4 w0 = wp[0], w1 = wp[1];
            bf16x8 xv, wv;
            xv[0] = (__bf16)x0.x; xv[1] = (__bf16)x0.y; xv[2] = (__bf16)x0.z; xv[3] = (__bf16)x0.w;
            xv[4] = (__bf16)x1.x; xv[5] = (__bf16)x1.y; xv[6] = (__bf16)x1.z; xv[7] = (__bf16)x1.w;
            wv[0] = (__bf16)w0.x; wv[1] = (__bf16)w0.y; wv[2] = (__bf16)w0.z; wv[3] = (__bf16)w0.w;
            wv[4] = (__bf16)w1.x; wv[5] = (__bf16)w1.y; wv[6] = (__bf16)w1.z; wv[7] = (__bf16)w1.w;
            *(bf16x8*)&Xs[lrow * 40 + lk] = xv;
            *(bf16x8*)&Ws[lrow * 40 + lk] = wv;
        }
        __syncthreads();
        bf16x8 a = *(const bf16x8*)&Xs[(wave * 16 + ln) * 40 + qd * 8];
        for (int c = 0; c < 4; ++c) {
            bf16x8 b = *(const bf16x8*)&Ws[(c * 16 + ln) * 40 + qd * 8];
            acc[c] = __builtin_amdgcn_mfma_f32_16x16x32_bf16(a, b, acc[c], 0, 0, 0);
        }
    }
    // C/D layout (verified m89/m91): col = lane&15, row = (lane>>4)*4 + reg
    for (int c = 0; c < 4; ++c) {
        const int n = n0 + c * 16 + ln;
        const float bv = bias[n];
        for (int r = 0; r < 4; ++r) {
            const int m = m0 + wave * 16 + qd * 4 + r;
            Y[(size_t)m * N + n] = acc[c][r] + bv;
        }
    }
}

// One block = (b, h, 4 consecutive q rows). Scores in fp32 LDS, softmax,
// write A rows (fp32), then PV -> O (fp32, [B,T,D] head-interleaved).
// O may alias the Q buffer (no __restrict__ on those): block (qi0,b,h) is
// the unique reader AND writer of (rows qi0..qi0+3, cols h*64..h*64+63),
// and reads Q into LDS (barrier) before writing O.
__global__ __launch_bounds__(256) void attn_kernel(const float* Qp,
                                                   const float* __restrict__ Kp,
                                                   const float* __restrict__ Vp,
                                                   float* __restrict__ Aout,
                                                   float* O) {
    const int t = threadIdx.x;
    const int qi0 = blockIdx.x * QB;
    const int bh = blockIdx.y;
    const int b = bh / HH;
    const int h = bh % HH;
    const int kmax = qi0 + QB - 1;
    const float scale = 0.125f;  // 1/sqrt(64)
    const float NEGBIG = -1e30f;

    __shared__ float q_tile[QB][DKK];
    __shared__ float s_tile[QB][TT];      // 32 KB
    __shared__ float wredm[4][QB];
    __shared__ float wreds[4][QB];
    __shared__ float pv_red[4][QB][DKK];  // 4 KB

    const float* kbase = Kp + (size_t)b * TT * DD + h * DKK;
    const float* vbase = Vp + (size_t)b * TT * DD + h * DKK;

    {  // load 4 q rows -> LDS
        const int r = t >> 6, d = t & 63;
        q_tile[r][d] = Qp[(size_t)(b * TT + qi0 + r) * DD + h * DKK + d];
    }
    __syncthreads();

    // ---- scores: s[r][ki] = (q_r . k_ki) * scale, causal-masked
    for (int ki = t; ki <= kmax; ki += 256) {
        const float4* kp = (const float4*)(kbase + (size_t)ki * DD);
        float dot[QB] = {0.f, 0.f, 0.f, 0.f};
        for (int dc = 0; dc < DKK / 4; ++dc) {
            const float4 kv = kp[dc];
            for (int r = 0; r < QB; ++r) {
                dot[r] += kv.x * q_tile[r][dc * 4 + 0] + kv.y * q_tile[r][dc * 4 + 1]
                        + kv.z * q_tile[r][dc * 4 + 2] + kv.w * q_tile[r][dc * 4 + 3];
            }
        }
        for (int r = 0; r < QB; ++r)
            s_tile[r][ki] = (ki <= qi0 + r) ? dot[r] * scale : NEGBIG;
    }

    // ---- row max (each thread reduces only entries it wrote)
    float lm[QB] = {NEGBIG, NEGBIG, NEGBIG, NEGBIG};
    for (int ki = t; ki <= kmax; ki += 256)
        for (int r = 0; r < QB; ++r) lm[r] = fmaxf(lm[r], s_tile[r][ki]);
    for (int off = 32; off > 0; off >>= 1)
        for (int r = 0; r < QB; ++r) lm[r] = fmaxf(lm[r], __shfl_down(lm[r], off, 64));
    if ((t & 63) == 0)
        for (int r = 0; r < QB; ++r) wredm[t >> 6][r] = lm[r];
    __syncthreads();
    float m[QB];
    for (int r = 0; r < QB; ++r)
        m[r] = fmaxf(fmaxf(wredm[0][r], wredm[1][r]), fmaxf(wredm[2][r], wredm[3][r]));

    // ---- exp + row sum (sum >= exp(max-m) = 1, so inv is finite)
    float ls[QB] = {0.f, 0.f, 0.f, 0.f};
    for (int ki = t; ki <= kmax; ki += 256) {
        for (int r = 0; r < QB; ++r) {
            const float e = __expf(s_tile[r][ki] - m[r]);  // masked -> 0
            s_tile[r][ki] = e;
            ls[r] += e;
        }
    }
    for (int off = 32; off > 0; off >>= 1)
        for (int r = 0; r < QB; ++r) ls[r] += __shfl_down(ls[r], off, 64);
    if ((t & 63) == 0)
        for (int r = 0; r < QB; ++r) wreds[t >> 6][r] = ls[r];
    __syncthreads();
    float inv[QB];
    for (int r = 0; r < QB; ++r)
        inv[r] = 1.0f / (wreds[0][r] + wreds[1][r] + wreds[2][r] + wreds[3][r]);

    // ---- normalize + write A (full rows; exact zeros above the diagonal)
    const size_t abase = ((size_t)(b * HH + h) * TT) * TT;
    for (int ki = t; ki < TT; ki += 256) {
        for (int r = 0; r < QB; ++r) {
            float a = 0.f;
            if (ki <= kmax) {
                a = s_tile[r][ki] * inv[r];
                s_tile[r][ki] = a;
            }
            Aout[abase + (size_t)(qi0 + r) * TT + ki] = a;
        }
    }
    __syncthreads();

    // ---- PV: O[r][dk] = sum_k a[r][k] * V[k][dk]
    {
        const int dk = t & 63;
        const int part = t >> 6;
        float acc[QB] = {0.f, 0.f, 0.f, 0.f};
        for (int kk = part; kk <= kmax; kk += 4) {
            const float vv = vbase[(size_t)kk * DD + dk];
            for (int r = 0; r < QB; ++r) acc[r] += s_tile[r][kk] * vv;
        }
        for (int r = 0; r < QB; ++r) pv_red[part][r][dk] = acc[r];
    }
    __syncthreads();
    {
        const int r = t >> 6;
        const int dk = t & 63;
        const float o = pv_red[0][r][dk] + pv_red[1][r][dk] + pv_red[2][r][dk] + pv_red[3][r][dk];
        O[(size_t)(b * TT + qi0 + r) * DD + h * DKK + dk] = o;
    }
}

extern "C" void kernel_launch(void* const* d_in, const int* in_sizes, int n_in,
                              void* d_out, int out_size, void* d_ws, size_t ws_size,
                              hipStream_t stream) {
    const float* q  = (const float*)d_in[0];
    const float* k  = (const float*)d_in[1];
    const float* v  = (const float*)d_in[2];
    // d_in[3] = attn_mask (int32 causal tril) -- causality hard-coded
    const float* Wq = (const float*)d_in[4];
    const float* bq = (const float*)d_in[5];
    const float* Wk = (const float*)d_in[6];
    const float* bk = (const float*)d_in[7];
    const float* Wv = (const float*)d_in[8];
    const float* bv = (const float*)d_in[9];
    const float* Wo = (const float*)d_in[10];
    const float* bo = (const float*)d_in[11];

    float* outp = (float*)d_out;                // [B,T,D]
    float* Aout = outp + (size_t)BB * TT * DD;  // [B,H,T,T]

    // workspace: Qp,Kp,Vp fp32 (8 MB each) = 24 MB. O aliases Qp
    // (race-free: per-block read-then-write of disjoint segments).
    float* Qp = (float*)d_ws;
    float* Kp = Qp + (size_t)BB * TT * DD;
    float* Vp = Kp + (size_t)BB * TT * DD;
    float* Ob = Qp;

    const int M = BB * TT;     // 4096
    dim3 gG(M / 64, DD / 64);  // (64, 8)

    gemm_bt<<<gG, 256, 0, stream>>>(q, Wq, bq, Qp, M, DD, DD);
    gemm_bt<<<gG, 256, 0, stream>>>(k, Wk, bk, Kp, M, DD, DD);
    gemm_bt<<<gG, 256, 0, stream>>>(v, Wv, bv, Vp, M, DD, DD);

    dim3 gA(TT / QB, BB * HH);  // (512, 16)
    attn_kernel<<<gA, 256, 0, stream>>>(Qp, Kp, Vp, Aout, Ob);

    gemm_bt<<<gG, 256, 0, stream>>>(Ob, Wo, bo, outp, M, DD, DD);
}

// Round 4
// 472.579 us; speedup vs baseline: 5.3776x; 5.3776x over previous
//
#include <hip/hip_runtime.h>
#include <hip/hip_bf16.h>

// SimpleMHA  B=2 T=2048 D=512 H=8 DK=64  -- fp32 in/out.
// d_out = out [B,T,D] fp32  ++  A [B,H,T,T] fp32.
#define BB 2
#define TT 2048
#define DD 512
#define HH 8
#define DKK 64

typedef __hip_bfloat16 bf16;
typedef __bf16 bf16x8 __attribute__((ext_vector_type(8)));
typedef float f32x4 __attribute__((ext_vector_type(4)));

__device__ inline bf16x8 cvt8(const float4 a, const float4 b) {
    bf16x8 r;
    r[0] = (__bf16)a.x; r[1] = (__bf16)a.y; r[2] = (__bf16)a.z; r[3] = (__bf16)a.w;
    r[4] = (__bf16)b.x; r[5] = (__bf16)b.y; r[6] = (__bf16)b.z; r[7] = (__bf16)b.w;
    return r;
}

// Y = X @ W^T + b.  X:[M,K] fp32, W:[N,K] fp32, bf16-MFMA compute.
// 128x64 block tile, BK=64. Wave w: rows [w*32, w*32+32), all 4 col-tiles.
__global__ __launch_bounds__(256) void gemm_bt(const float* __restrict__ X,
                                               const float* __restrict__ W,
                                               const float* __restrict__ bias,
                                               float* __restrict__ Y,
                                               int M, int N, int K) {
    const int m0 = blockIdx.x * 128;
    const int n0 = blockIdx.y * 64;
    const int t = threadIdx.x;
    const int wv = t >> 6, lane = t & 63, ln = lane & 15, qd = lane >> 4;

    // pitch 72 bf16 = 36 dwords: row stride 4 banks; frag b128 reads <=2-way (free)
    __shared__ __align__(16) __bf16 Xs[128 * 72];
    __shared__ __align__(16) __bf16 Ws[64 * 72];

    f32x4 acc[2][4];
    for (int rt = 0; rt < 2; ++rt)
        for (int c = 0; c < 4; ++c) acc[rt][c] = (f32x4){0.f, 0.f, 0.f, 0.f};

    const int srow = t >> 2;        // 0..63
    const int scol = (t & 3) * 16;  // 0,16,32,48

    for (int k0 = 0; k0 < K; k0 += 64) {
        __syncthreads();
        for (int rr = 0; rr < 2; ++rr) {
            const float4* xp = (const float4*)(X + (size_t)(m0 + rr * 64 + srow) * K + k0 + scol);
            const float4 x0 = xp[0], x1 = xp[1], x2 = xp[2], x3 = xp[3];
            *(bf16x8*)&Xs[(rr * 64 + srow) * 72 + scol] = cvt8(x0, x1);
            *(bf16x8*)&Xs[(rr * 64 + srow) * 72 + scol + 8] = cvt8(x2, x3);
        }
        {
            const float4* wp = (const float4*)(W + (size_t)(n0 + srow) * K + k0 + scol);
            const float4 w0 = wp[0], w1 = wp[1], w2 = wp[2], w3 = wp[3];
            *(bf16x8*)&Ws[srow * 72 + scol] = cvt8(w0, w1);
            *(bf16x8*)&Ws[srow * 72 + scol + 8] = cvt8(w2, w3);
        }
        __syncthreads();
        for (int kh = 0; kh < 2; ++kh) {
            const bf16x8 a0 = *(const bf16x8*)&Xs[(wv * 32 + ln) * 72 + kh * 32 + qd * 8];
            const bf16x8 a1 = *(const bf16x8*)&Xs[(wv * 32 + 16 + ln) * 72 + kh * 32 + qd * 8];
            for (int c = 0; c < 4; ++c) {
                const bf16x8 b = *(const bf16x8*)&Ws[(c * 16 + ln) * 72 + kh * 32 + qd * 8];
                acc[0][c] = __builtin_amdgcn_mfma_f32_16x16x32_bf16(a0, b, acc[0][c], 0, 0, 0);
                acc[1][c] = __builtin_amdgcn_mfma_f32_16x16x32_bf16(a1, b, acc[1][c], 0, 0, 0);
            }
        }
    }
    // C/D layout: col = lane&15, row = (lane>>4)*4 + reg  (m89/m91)
    for (int rt = 0; rt < 2; ++rt)
        for (int c = 0; c < 4; ++c) {
            const int n = n0 + c * 16 + ln;
            const float bv = bias[n];
            for (int r = 0; r < 4; ++r) {
                const int m = m0 + wv * 32 + rt * 16 + qd * 4 + r;
                Y[(size_t)m * N + n] = acc[rt][c][r] + bv;
            }
        }
}

// Flash-style MFMA attention. Block = (qt, b*h): 64 q-rows of one head.
// Pass 1: online (m,l) over k-tiles via MFMA QK^T. Pass 2: recompute S,
// write A fp32, O += P@V via MFMA (V transposed through LDS). Zero-fill
// A above the diagonal. O aliases Qp: this block is the unique reader and
// writer of its (64-row x 64-col) segment, read (pass start) before write.
__global__ __launch_bounds__(256) void attn_kernel(const float* Qp,
                                                   const float* __restrict__ Kp,
                                                   const float* __restrict__ Vp,
                                                   float* __restrict__ Aout,
                                                   float* O) {
    const int t = threadIdx.x;
    const int qt = blockIdx.x;  // q-tile 0..31
    const int bh = blockIdx.y;
    const int b = bh >> 3, h = bh & 7;
    const int wv = t >> 6, lane = t & 63, ln = lane & 15, qd = lane >> 4;
    const float scale = 0.125f;  // 1/sqrt(64)

    __shared__ __align__(16) __bf16 Qs[64 * 72];
    __shared__ __align__(16) __bf16 Ks[64 * 72];
    __shared__ __align__(16) __bf16 Ps[64 * 72];
    // pitch 70 bf16 = 35 dwords (odd): dk-row stride 3 banks; the 16-dk
    // transpose scatter lands 2-way max (free), frag reads ~2-way.
    __shared__ __align__(16) __bf16 Vts[64 * 70];

    const int srow = t >> 2;        // 0..63
    const int scol = (t & 3) * 16;  // 0,16,32,48

    const float* qbase = Qp + (size_t)(b * TT + qt * 64) * DD + h * DKK;
    const float* kbase = Kp + (size_t)b * TT * DD + h * DKK;
    const float* vbase = Vp + (size_t)b * TT * DD + h * DKK;

    {  // stage Q tile (64x64) -> bf16 LDS
        const float4* qp4 = (const float4*)(qbase + (size_t)srow * DD + scol);
        const float4 q0 = qp4[0], q1 = qp4[1], q2 = qp4[2], q3 = qp4[3];
        *(bf16x8*)&Qs[srow * 72 + scol] = cvt8(q0, q1);
        *(bf16x8*)&Qs[srow * 72 + scol + 8] = cvt8(q2, q3);
    }
    __syncthreads();
    // Q fragments are loop-invariant: load once
    const bf16x8 qa0 = *(const bf16x8*)&Qs[(wv * 16 + ln) * 72 + qd * 8];
    const bf16x8 qa1 = *(const bf16x8*)&Qs[(wv * 16 + ln) * 72 + 32 + qd * 8];

    float m_run[4] = {-1e30f, -1e30f, -1e30f, -1e30f};
    float l_run[4] = {0.f, 0.f, 0.f, 0.f};

    // ================= pass 1: online m, l =================
    for (int kt = 0; kt <= qt; ++kt) {
        __syncthreads();
        {
            const float4* kp4 = (const float4*)(kbase + (size_t)(kt * 64 + srow) * DD + scol);
            const float4 k0 = kp4[0], k1 = kp4[1], k2 = kp4[2], k3 = kp4[3];
            *(bf16x8*)&Ks[srow * 72 + scol] = cvt8(k0, k1);
            *(bf16x8*)&Ks[srow * 72 + scol + 8] = cvt8(k2, k3);
        }
        __syncthreads();
        f32x4 S[4];
        for (int c = 0; c < 4; ++c) {
            const bf16x8 b0 = *(const bf16x8*)&Ks[(c * 16 + ln) * 72 + qd * 8];
            const bf16x8 b1 = *(const bf16x8*)&Ks[(c * 16 + ln) * 72 + 32 + qd * 8];
            f32x4 s = (f32x4){0.f, 0.f, 0.f, 0.f};
            s = __builtin_amdgcn_mfma_f32_16x16x32_bf16(qa0, b0, s, 0, 0, 0);
            s = __builtin_amdgcn_mfma_f32_16x16x32_bf16(qa1, b1, s, 0, 0, 0);
            for (int r = 0; r < 4; ++r) S[c][r] = s[r] * scale;
        }
        if (kt == qt) {  // diagonal tile: mask k > q
            for (int c = 0; c < 4; ++c)
                for (int r = 0; r < 4; ++r)
                    if (c * 16 + ln > wv * 16 + qd * 4 + r) S[c][r] = -1e30f;
        }
        for (int r = 0; r < 4; ++r) {
            float tm = fmaxf(fmaxf(S[0][r], S[1][r]), fmaxf(S[2][r], S[3][r]));
            tm = fmaxf(tm, __shfl_xor(tm, 1, 64));
            tm = fmaxf(tm, __shfl_xor(tm, 2, 64));
            tm = fmaxf(tm, __shfl_xor(tm, 4, 64));
            tm = fmaxf(tm, __shfl_xor(tm, 8, 64));  // row max over 16-lane group
            const float mn = fmaxf(m_run[r], tm);
            const float corr = __expf(m_run[r] - mn);
            const float s = __expf(S[0][r] - mn) + __expf(S[1][r] - mn)
                          + __expf(S[2][r] - mn) + __expf(S[3][r] - mn);
            l_run[r] = l_run[r] * corr + s;
            m_run[r] = mn;
        }
    }
    float inv_l[4];
    for (int r = 0; r < 4; ++r) {
        float l = l_run[r];
        l += __shfl_xor(l, 1, 64);
        l += __shfl_xor(l, 2, 64);
        l += __shfl_xor(l, 4, 64);
        l += __shfl_xor(l, 8, 64);
        inv_l[r] = 1.0f / l;  // >= exp(0) = 1 from the diagonal, never 0
    }

    // ================= pass 2: A write + O = P@V =================
    f32x4 Oacc[4];
    for (int c = 0; c < 4; ++c) Oacc[c] = (f32x4){0.f, 0.f, 0.f, 0.f};
    const size_t abase = ((size_t)bh * TT + qt * 64) * TT;
    const int rowl = wv * 16 + qd * 4;

    for (int kt = 0; kt <= qt; ++kt) {
        __syncthreads();  // prior-iter Ks/Vts/Ps reads complete
        {
            const float4* kp4 = (const float4*)(kbase + (size_t)(kt * 64 + srow) * DD + scol);
            const float4 k0 = kp4[0], k1 = kp4[1], k2 = kp4[2], k3 = kp4[3];
            *(bf16x8*)&Ks[srow * 72 + scol] = cvt8(k0, k1);
            *(bf16x8*)&Ks[srow * 72 + scol + 8] = cvt8(k2, k3);
        }
        {   // V tile transposed: Vts[dk][key]
            const float4* vp4 = (const float4*)(vbase + (size_t)(kt * 64 + srow) * DD + scol);
            const float4 v0 = vp4[0], v1 = vp4[1], v2 = vp4[2], v3 = vp4[3];
            Vts[(scol + 0) * 70 + srow] = (__bf16)v0.x;
            Vts[(scol + 1) * 70 + srow] = (__bf16)v0.y;
            Vts[(scol + 2) * 70 + srow] = (__bf16)v0.z;
            Vts[(scol + 3) * 70 + srow] = (__bf16)v0.w;
            Vts[(scol + 4) * 70 + srow] = (__bf16)v1.x;
            Vts[(scol + 5) * 70 + srow] = (__bf16)v1.y;
            Vts[(scol + 6) * 70 + srow] = (__bf16)v1.z;
            Vts[(scol + 7) * 70 + srow] = (__bf16)v1.w;
            Vts[(scol + 8) * 70 + srow] = (__bf16)v2.x;
            Vts[(scol + 9) * 70 + srow] = (__bf16)v2.y;
            Vts[(scol + 10) * 70 + srow] = (__bf16)v2.z;
            Vts[(scol + 11) * 70 + srow] = (__bf16)v2.w;
            Vts[(scol + 12) * 70 + srow] = (__bf16)v3.x;
            Vts[(scol + 13) * 70 + srow] = (__bf16)v3.y;
            Vts[(scol + 14) * 70 + srow] = (__bf16)v3.z;
            Vts[(scol + 15) * 70 + srow] = (__bf16)v3.w;
        }
        __syncthreads();
        f32x4 S[4];
        for (int c = 0; c < 4; ++c) {
            const bf16x8 b0 = *(const bf16x8*)&Ks[(c * 16 + ln) * 72 + qd * 8];
            const bf16x8 b1 = *(const bf16x8*)&Ks[(c * 16 + ln) * 72 + 32 + qd * 8];
            f32x4 s = (f32x4){0.f, 0.f, 0.f, 0.f};
            s = __builtin_amdgcn_mfma_f32_16x16x32_bf16(qa0, b0, s, 0, 0, 0);
            s = __builtin_amdgcn_mfma_f32_16x16x32_bf16(qa1, b1, s, 0, 0, 0);
            for (int r = 0; r < 4; ++r) S[c][r] = s[r] * scale;
        }
        if (kt == qt) {
            for (int c = 0; c < 4; ++c)
                for (int r = 0; r < 4; ++r)
                    if (c * 16 + ln > wv * 16 + qd * 4 + r) S[c][r] = -1e30f;
        }
        for (int c = 0; c < 4; ++c) {
            for (int r = 0; r < 4; ++r) {
                const float p = __expf(S[c][r] - m_run[r]) * inv_l[r];  // masked -> 0
                Aout[abase + (size_t)(rowl + r) * TT + kt * 64 + c * 16 + ln] = p;
                Ps[(rowl + r) * 72 + c * 16 + ln] = (__bf16)p;
            }
        }
        __syncthreads();  // Ps visible
        const bf16x8 p0 = *(const bf16x8*)&Ps[(wv * 16 + ln) * 72 + qd * 8];
        const bf16x8 p1 = *(const bf16x8*)&Ps[(wv * 16 + ln) * 72 + 32 + qd * 8];
        for (int c = 0; c < 4; ++c) {
            const bf16x8 v0 = *(const bf16x8*)&Vts[(c * 16 + ln) * 70 + qd * 8];
            const bf16x8 v1 = *(const bf16x8*)&Vts[(c * 16 + ln) * 70 + 32 + qd * 8];
            Oacc[c] = __builtin_amdgcn_mfma_f32_16x16x32_bf16(p0, v0, Oacc[c], 0, 0, 0);
            Oacc[c] = __builtin_amdgcn_mfma_f32_16x16x32_bf16(p1, v1, Oacc[c], 0, 0, 0);
        }
    }

    {  // zero-fill A above the diagonal block (cols (qt+1)*64 .. TT)
        const float4 z = (float4){0.f, 0.f, 0.f, 0.f};
        float* arow = Aout + abase + (size_t)(t >> 2) * TT;
        for (int col = (qt + 1) * 64 + (t & 3) * 4; col < TT; col += 16)
            *(float4*)(arow + col) = z;
    }

    for (int c = 0; c < 4; ++c)  // O (aliases Q segment of this block)
        for (int r = 0; r < 4; ++r)
            O[(size_t)(b * TT + qt * 64 + rowl + r) * DD + h * DKK + c * 16 + ln] = Oacc[c][r];
}

extern "C" void kernel_launch(void* const* d_in, const int* in_sizes, int n_in,
                              void* d_out, int out_size, void* d_ws, size_t ws_size,
                              hipStream_t stream) {
    const float* q  = (const float*)d_in[0];
    const float* k  = (const float*)d_in[1];
    const float* v  = (const float*)d_in[2];
    // d_in[3] = attn_mask (causal tril) -- causality hard-coded
    const float* Wq = (const float*)d_in[4];
    const float* bq = (const float*)d_in[5];
    const float* Wk = (const float*)d_in[6];
    const float* bk = (const float*)d_in[7];
    const float* Wv = (const float*)d_in[8];
    const float* bv = (const float*)d_in[9];
    const float* Wo = (const float*)d_in[10];
    const float* bo = (const float*)d_in[11];

    float* outp = (float*)d_out;                // [B,T,D]
    float* Aout = outp + (size_t)BB * TT * DD;  // [B,H,T,T]

    // workspace: Qp,Kp,Vp fp32 (8 MB each) = 24 MB. O aliases Qp.
    float* Qp = (float*)d_ws;
    float* Kp = Qp + (size_t)BB * TT * DD;
    float* Vp = Kp + (size_t)BB * TT * DD;
    float* Ob = Qp;

    const int M = BB * TT;      // 4096
    dim3 gG(M / 128, DD / 64);  // (32, 8)

    gemm_bt<<<gG, 256, 0, stream>>>(q, Wq, bq, Qp, M, DD, DD);
    gemm_bt<<<gG, 256, 0, stream>>>(k, Wk, bk, Kp, M, DD, DD);
    gemm_bt<<<gG, 256, 0, stream>>>(v, Wv, bv, Vp, M, DD, DD);

    dim3 gA(TT / 64, BB * HH);  // (32, 16)
    attn_kernel<<<gA, 256, 0, stream>>>(Qp, Kp, Vp, Aout, Ob);

    gemm_bt<<<gG, 256, 0, stream>>>(Ob, Wo, bo, outp, M, DD, DD);
}